// Round 16
// baseline (223.491 us; speedup 1.0000x reference)
//
#include <hip/hip_runtime.h>
#include <hip/hip_bf16.h>

// Problem constants
#define BB 4
#define LL 900
#define DMODEL 256
#define DSTATE 16
#define DINNER 512
#define DTRANK 16
#define BL (BB*LL)          // 3600
#define NC 75               // scan chunks
#define LC 12               // steps per chunk; NC*LC == LL

typedef __bf16 bf16x8 __attribute__((ext_vector_type(8)));
typedef __bf16 bf16x4 __attribute__((ext_vector_type(4)));
typedef float f32x4 __attribute__((ext_vector_type(4)));

__device__ __forceinline__ float silu_f(float v) { return v / (1.f + __expf(-v)); }

// load 8 fp32 and convert to bf16x8 (RNE — bit-identical to a pre-conversion pass)
__device__ __forceinline__ bf16x8 ldcvt8(const float* __restrict__ p)
{
    const f32x4* q = reinterpret_cast<const f32x4*>(p);
    f32x4 v0 = q[0], v1 = q[1];
    bf16x8 r;
    #pragma unroll
    for (int j = 0; j < 4; ++j) { r[j] = (__bf16)v0[j]; r[4 + j] = (__bf16)v1[j]; }
    return r;
}

// ---------------------------------------------------------------------------
// gemm1: xz = hidden @ W_in^T (M=3600,N=1024,K=256), fp32 operands converted
// on the fly to bf16 MFMA fragments; fused silu epilogue. 2400 waves.
// ---------------------------------------------------------------------------
__launch_bounds__(256)
__global__ void gemm_silu(const float* __restrict__ A, const float* __restrict__ B,
                          __bf16* __restrict__ xb, __bf16* __restrict__ zb)
{
    constexpr int WM = 3, WN = 2, K = 256, nk = K >> 5;
    constexpr int M = BL, N = 2 * DINNER;
    int wave = (blockIdx.x * 256 + threadIdx.x) >> 6;
    int ntN = N / (16 * WN);
    if (wave >= (M / (16 * WM)) * ntN) return;
    int tm = wave / ntN, tn = wave % ntN;
    int lane = threadIdx.x & 63, q = lane >> 4, r = lane & 15;

    const float* Ar[WM]; const float* Br[WN];
    #pragma unroll
    for (int mi = 0; mi < WM; ++mi)
        Ar[mi] = A + (size_t)(tm * 48 + mi * 16 + r) * K;
    #pragma unroll
    for (int ni = 0; ni < WN; ++ni)
        Br[ni] = B + (size_t)(tn * 32 + ni * 16 + r) * K;
    f32x4 acc[WM][WN];
    #pragma unroll
    for (int mi = 0; mi < WM; ++mi)
        #pragma unroll
        for (int ni = 0; ni < WN; ++ni) acc[mi][ni] = (f32x4){0.f,0.f,0.f,0.f};

    #pragma unroll
    for (int kk = 0; kk < nk; ++kk) {
        int idx = kk * 4 + q;
        bf16x8 av[WM], bv[WN];
        #pragma unroll
        for (int mi = 0; mi < WM; ++mi) av[mi] = ldcvt8(Ar[mi] + idx * 8);
        #pragma unroll
        for (int ni = 0; ni < WN; ++ni) bv[ni] = ldcvt8(Br[ni] + idx * 8);
        #pragma unroll
        for (int mi = 0; mi < WM; ++mi)
            #pragma unroll
            for (int ni = 0; ni < WN; ++ni)
                acc[mi][ni] = __builtin_amdgcn_mfma_f32_16x16x32_bf16(av[mi], bv[ni], acc[mi][ni], 0, 0, 0);
    }
    #pragma unroll
    for (int mi = 0; mi < WM; ++mi)
        #pragma unroll
        for (int ni = 0; ni < WN; ++ni) {
            int col = tn * 32 + ni * 16 + r;
            #pragma unroll
            for (int i = 0; i < 4; ++i) {
                int row = tm * 48 + mi * 16 + q * 4 + i;
                float s = silu_f(acc[mi][ni][i]);
                if (col < DINNER) xb[(size_t)row * DINNER + col] = (__bf16)s;
                else              zb[(size_t)row * DINNER + (col - DINNER)] = (__bf16)s;
            }
        }
}

// ---------------------------------------------------------------------------
// gemm2 + dt fused: x_dbl = x @ W_xproj^T (M=3600,N=48,K=512), KS=4 K-split
// combined in LDS, then dt = softplus(...) -> dtb (bf16). W_xproj converted
// on the fly. Blocks 0-15 also zero the ymean accumulator (needed 2 launches
// later by pass3's atomics).
// ---------------------------------------------------------------------------
__launch_bounds__(256)
__global__ void gemm2_dt(const __bf16* __restrict__ A, const float* __restrict__ B,
                         const float* __restrict__ Wdt, const float* __restrict__ bdt,
                         float* __restrict__ dtBC, __bf16* __restrict__ dtb,
                         float* __restrict__ ymean)
{
    constexpr int WN = 3, K = 512, KSL = 128, nk = KSL >> 5;   // 4 chunks
    __shared__ float lds[4][16 * 48];
    int tm = blockIdx.x;                       // 225 tiles (16 rows each)
    if (tm < 16) ymean[tm * 256 + threadIdx.x] = 0.f;   // zero 4096-elem accum
    int wv = threadIdx.x >> 6, kOff = wv * KSL;
    int lane = threadIdx.x & 63, q = lane >> 4, r = lane & 15;

    const bf16x8* Ar = (const bf16x8*)(A + (size_t)(tm * 16 + r) * K + kOff);
    const float* Br[WN];
    #pragma unroll
    for (int ni = 0; ni < WN; ++ni)
        Br[ni] = B + (size_t)(ni * 16 + r) * K + kOff;
    f32x4 acc[WN];
    #pragma unroll
    for (int ni = 0; ni < WN; ++ni) acc[ni] = (f32x4){0.f,0.f,0.f,0.f};

    #pragma unroll
    for (int kk = 0; kk < nk; ++kk) {
        int idx = kk * 4 + q;
        bf16x8 av = Ar[idx];
        #pragma unroll
        for (int ni = 0; ni < WN; ++ni)
            acc[ni] = __builtin_amdgcn_mfma_f32_16x16x32_bf16(av, ldcvt8(Br[ni] + idx * 8), acc[ni], 0, 0, 0);
    }
    #pragma unroll
    for (int ni = 0; ni < WN; ++ni) {
        int col = ni * 16 + r;
        #pragma unroll
        for (int i = 0; i < 4; ++i)
            lds[wv][(q * 4 + i) * 48 + col] = acc[ni][i];
    }
    __syncthreads();
    for (int e = threadIdx.x; e < 16 * 48; e += 256) {
        float s = lds[0][e] + lds[1][e] + lds[2][e] + lds[3][e];
        lds[0][e] = s;
        int row = e / 48, col = e % 48;
        dtBC[(size_t)(tm * 16 + row) * 48 + col] = s;
    }
    __syncthreads();
    for (int it = 0; it < 32; ++it) {
        int e = threadIdx.x + it * 256;        // 8192
        int row = e >> 9, d = e & 511;
        const float* wr = Wdt + (size_t)d * DTRANK;
        float s = bdt[d];
        #pragma unroll
        for (int k = 0; k < DTRANK; ++k) s = fmaf(lds[0][row * 48 + k], wr[k], s);
        float dtv = (s > 15.f) ? s : __logf(1.f + __expf(s));
        dtb[(size_t)(tm * 16 + row) * DINNER + d] = (__bf16)dtv;
    }
}

// ---------------------------------------------------------------------------
// Scan pass 1: per-chunk zero-init run -> Q (end state, bf16), sdt (scalar).
// Q layout: [bd][c][n][d] (d fastest). sdt: [bd][c][d].
// ---------------------------------------------------------------------------
__global__ void scan_pass1(const __bf16* __restrict__ dtb,
                           const __bf16* __restrict__ xb,
                           const float* __restrict__ dtBC,
                           const float* __restrict__ AlogF, const float* __restrict__ AlogB,
                           float* __restrict__ sdtBuf, __bf16* __restrict__ Qbuf)
{
    int b = blockIdx.z, dir = blockIdx.y;
    int c = blockIdx.x >> 2, dgrp = blockIdx.x & 3;
    int d = dgrp * 128 + threadIdx.x;
    const float* Alog = dir ? AlogB : AlogF;
    float a2[DSTATE];
    #pragma unroll
    for (int n = 0; n < DSTATE; ++n) a2[n] = -__expf(Alog[d * DSTATE + n]) * 1.44269504f;
    float h[DSTATE];
    #pragma unroll
    for (int n = 0; n < DSTATE; ++n) h[n] = 0.f;
    float sdt = 0.f;

    #pragma unroll 4
    for (int il = 0; il < LC; ++il) {
        int i = c * LC + il;
        int l = dir ? (LL - 1 - i) : i;
        size_t base = (size_t)b * LL + l;
        float dtv = (float)dtb[base * DINNER + d];
        float u = (float)xb[base * DINNER + d];
        float du = dtv * u;
        const f32x4* Bp = (const f32x4*)(dtBC + base * 48 + DTRANK);
        f32x4 Bq[4];
        #pragma unroll
        for (int j = 0; j < 4; ++j) Bq[j] = Bp[j];
        sdt += dtv;
        #pragma unroll
        for (int n = 0; n < DSTATE; ++n)
            h[n] = fmaf(exp2f(dtv * a2[n]), h[n], du * Bq[n >> 2][n & 3]);
    }
    int bd = b * 2 + dir;
    sdtBuf[((size_t)bd * NC + c) * DINNER + d] = sdt;
    size_t o = (((size_t)bd * NC + c) * DSTATE) * DINNER + d;
    #pragma unroll
    for (int n = 0; n < DSTATE; ++n)
        Qbuf[o + (size_t)n * DINNER] = (__bf16)h[n];
}

// Pass 2: stitch in place on Qbuf (H0 overwrites Q); P recomputed from sdt.
__global__ void scan_stitch(const float* __restrict__ sdtBuf,
                            const float* __restrict__ AlogF, const float* __restrict__ AlogB,
                            __bf16* __restrict__ Qbuf)
{
    int idx = blockIdx.x * 256 + threadIdx.x;   // 65536
    int bd = idx >> 13;
    int rem = idx & 8191;           // n*512 + d
    int n = rem >> 9, d = rem & 511;
    const float* Alog = (bd & 1) ? AlogB : AlogF;
    float a2 = -__expf(Alog[d * DSTATE + n]) * 1.44269504f;
    size_t qbase = (size_t)bd * NC * 8192 + rem;
    size_t sbase = (size_t)bd * NC * DINNER + d;
    float H = 0.f;
    for (int cb = 0; cb < NC; cb += 15) {
        float Qv[15], Sv[15];
        #pragma unroll
        for (int j = 0; j < 15; ++j) {
            Qv[j] = (float)Qbuf[qbase + (size_t)(cb + j) * 8192];
            Sv[j] = sdtBuf[sbase + (size_t)(cb + j) * DINNER];
        }
        #pragma unroll
        for (int j = 0; j < 15; ++j) {
            Qbuf[qbase + (size_t)(cb + j) * 8192] = (__bf16)H;   // H0 for chunk
            H = fmaf(exp2f(Sv[j] * a2), H, Qv[j]);
        }
    }
}

// Pass 3: re-run chunk from true initial state (bf16 H0 in Qbuf); emit y;
// accumulate the L-mean numerator straight into ymean via atomics.
__global__ void scan_pass3(const __bf16* __restrict__ dtb,
                           const __bf16* __restrict__ xb,
                           const float* __restrict__ dtBC,
                           const float* __restrict__ AlogF, const float* __restrict__ AlogB,
                           const float* __restrict__ Df, const float* __restrict__ Db,
                           const __bf16* __restrict__ zb,
                           const __bf16* __restrict__ H0buf,
                           __bf16* __restrict__ yb,        // [B,L,1024]
                           float* __restrict__ ymean)      // [B,1024] (pre-zeroed)
{
    int b = blockIdx.z, dir = blockIdx.y;
    int c = blockIdx.x >> 2, dgrp = blockIdx.x & 3;
    int d = dgrp * 128 + threadIdx.x;
    const float* Alog = dir ? AlogB : AlogF;
    float a2[DSTATE];
    #pragma unroll
    for (int n = 0; n < DSTATE; ++n) a2[n] = -__expf(Alog[d * DSTATE + n]) * 1.44269504f;
    float Dd = dir ? Db[d] : Df[d];
    size_t o = (((size_t)(b * 2 + dir) * NC + c) * DSTATE) * DINNER + d;
    float h[DSTATE];
    #pragma unroll
    for (int n = 0; n < DSTATE; ++n) h[n] = (float)H0buf[o + (size_t)n * DINNER];
    float ysum = 0.f;

    #pragma unroll 4
    for (int il = 0; il < LC; ++il) {
        int i = c * LC + il;
        int l = dir ? (LL - 1 - i) : i;
        size_t base = (size_t)b * LL + l;
        float dtv = (float)dtb[base * DINNER + d];
        float u = (float)xb[base * DINNER + d];
        float du = dtv * u;
        const f32x4* Bp = (const f32x4*)(dtBC + base * 48 + DTRANK);
        f32x4 Bq[4], Cq[4];
        #pragma unroll
        for (int j = 0; j < 4; ++j) Bq[j] = Bp[j];
        #pragma unroll
        for (int j = 0; j < 4; ++j) Cq[j] = Bp[4 + j];
        float p = 0.f;
        #pragma unroll
        for (int n = 0; n < DSTATE; ++n) {
            h[n] = fmaf(exp2f(dtv * a2[n]), h[n], du * Bq[n >> 2][n & 3]);
            p = fmaf(h[n], Cq[n >> 2][n & 3], p);
        }
        float zg = (float)zb[base * DINNER + d];
        float yv = (p + Dd * u) * zg;
        size_t yo = base * (2 * DINNER) + dir * DINNER + d;
        yb[yo] = (__bf16)yv;
        ysum += yv;
    }
    atomicAdd(&ymean[b * 1024 + dir * DINNER + d], ysum);
}

// gemv: one wave per (b,j); 4096 waves; fp32 weights (read once each).
// vout = [sigmoid]( dot(vin, W[j]) * scl + bias[j] )
template<int SIG>
__global__ void gemv1024(const float* __restrict__ vin,
                         const float* __restrict__ W,
                         const float* __restrict__ bias,
                         float* __restrict__ vout, float scl)
{
    int wv = (blockIdx.x * blockDim.x + threadIdx.x) >> 6;
    int b = wv >> 10, j = wv & 1023;
    int lane = threadIdx.x & 63;
    const float* wr = W + (size_t)j * 1024;
    const float* vr = vin + (size_t)b * 1024;
    float s = 0.f;
    for (int k = lane; k < 1024; k += 64) s = fmaf(vr[k], wr[k], s);
    #pragma unroll
    for (int o = 32; o; o >>= 1) s += __shfl_xor(s, o);
    if (lane == 0) {
        s = s * scl + bias[j];
        vout[wv] = SIG ? (1.f / (1.f + __expf(-s))) : s;
    }
}

// ---------------------------------------------------------------------------
// gemm8: out = (y ∘ g) @ W_out^T (M=3600,N=256,K=1024), KS=4 LDS-combined.
// One 48x32 tile per block; 4 waves = 4 K-slices of 256. g applied to the
// A fragment in fp32 right before MFMA; W_out converted on the fly.
// ---------------------------------------------------------------------------
__launch_bounds__(256)
__global__ void gemm8_comb(const __bf16* __restrict__ A, const float* __restrict__ B,
                           const float* __restrict__ g,   // [BB,1024]
                           float* __restrict__ out)
{
    constexpr int WM = 3, WN = 2, K = 1024, KSL = 256, nk = KSL >> 5;  // 8 chunks
    constexpr int N = DMODEL, ntN = N / (16 * WN);                      // 8
    __shared__ float lds[4][48 * 32];
    int ks = threadIdx.x >> 6;
    int tIdx = blockIdx.x;                     // 600 tiles
    int tm = tIdx / ntN, tn = tIdx % ntN;
    int kOff = ks * KSL;
    int lane = threadIdx.x & 63, q = lane >> 4, r = lane & 15;

    const bf16x8* Ar[WM]; const float* Br[WN];
    const float* gp[WM];
    #pragma unroll
    for (int mi = 0; mi < WM; ++mi) {
        int grow = tm * 48 + mi * 16 + r;
        Ar[mi] = (const bf16x8*)(A + (size_t)grow * K + kOff);
        gp[mi] = g + (grow / LL) * 1024 + kOff;
    }
    #pragma unroll
    for (int ni = 0; ni < WN; ++ni)
        Br[ni] = B + (size_t)(tn * 32 + ni * 16 + r) * K + kOff;
    f32x4 acc[WM][WN];
    #pragma unroll
    for (int mi = 0; mi < WM; ++mi)
        #pragma unroll
        for (int ni = 0; ni < WN; ++ni) acc[mi][ni] = (f32x4){0.f,0.f,0.f,0.f};

    #pragma unroll
    for (int kk = 0; kk < nk; ++kk) {
        int idx = kk * 4 + q;
        bf16x8 av[WM], bv[WN];
        #pragma unroll
        for (int mi = 0; mi < WM; ++mi) {
            bf16x8 a = Ar[mi][idx];
            const f32x4* gv = (const f32x4*)(gp[mi] + idx * 8);
            f32x4 g0 = gv[0], g1 = gv[1];
            #pragma unroll
            for (int j = 0; j < 4; ++j) a[j] = (__bf16)((float)a[j] * g0[j]);
            #pragma unroll
            for (int j = 0; j < 4; ++j) a[4 + j] = (__bf16)((float)a[4 + j] * g1[j]);
            av[mi] = a;
        }
        #pragma unroll
        for (int ni = 0; ni < WN; ++ni) bv[ni] = ldcvt8(Br[ni] + idx * 8);
        #pragma unroll
        for (int mi = 0; mi < WM; ++mi)
            #pragma unroll
            for (int ni = 0; ni < WN; ++ni)
                acc[mi][ni] = __builtin_amdgcn_mfma_f32_16x16x32_bf16(av[mi], bv[ni], acc[mi][ni], 0, 0, 0);
    }
    #pragma unroll
    for (int mi = 0; mi < WM; ++mi)
        #pragma unroll
        for (int ni = 0; ni < WN; ++ni) {
            int col = ni * 16 + r;
            #pragma unroll
            for (int i = 0; i < 4; ++i)
                lds[ks][(mi * 16 + q * 4 + i) * 32 + col] = acc[mi][ni][i];
        }
    __syncthreads();
    for (int e = threadIdx.x; e < 1536; e += 256) {
        int row = e >> 5, col = e & 31;
        int gm = tm * 48 + row, gn = tn * 32 + col;
        out[(size_t)gm * N + gn] = lds[0][e] + lds[1][e] + lds[2][e] + lds[3][e];
    }
}

// ---------------------------------------------------------------------------
extern "C" void kernel_launch(void* const* d_in, const int* in_sizes, int n_in,
                              void* d_out, int out_size, void* d_ws, size_t ws_size,
                              hipStream_t stream)
{
    const float* hidden  = (const float*)d_in[0];
    const float* W_in    = (const float*)d_in[1];
    const float* W_xproj = (const float*)d_in[2];
    const float* W_dt    = (const float*)d_in[3];
    const float* b_dt    = (const float*)d_in[4];
    const float* A_log_f = (const float*)d_in[5];
    const float* A_log_b = (const float*)d_in[6];
    const float* D_f     = (const float*)d_in[7];
    const float* D_b     = (const float*)d_in[8];
    const float* W_glob  = (const float*)d_in[9];
    const float* b_glob  = (const float*)d_in[10];
    const float* W_gate  = (const float*)d_in[11];
    const float* b_gate  = (const float*)d_in[12];
    const float* W_out   = (const float*)d_in[13];
    float* out = (float*)d_out;

    // workspace (~31 MB)
    char* w = (char*)d_ws;
    __bf16* xb    = (__bf16*)w; w += (size_t)BL * DINNER * 2;            // 3.69 MB
    __bf16* zb    = (__bf16*)w; w += (size_t)BL * DINNER * 2;            // 3.69 MB
    float* dtBC   = (float*)w;  w += (size_t)BL * 48 * 4;                // 0.69 MB
    __bf16* dtb   = (__bf16*)w; w += (size_t)BL * DINNER * 2;            // 3.69 MB
    __bf16* yb    = (__bf16*)w; w += (size_t)BL * 2 * DINNER * 2;        // 7.37 MB
    float* ymean  = (float*)w;  w += (size_t)BB * 1024 * 4;
    float* t1     = (float*)w;  w += (size_t)BB * 1024 * 4;
    float* gbuf   = (float*)w;  w += (size_t)BB * 1024 * 4;
    float* sdtBuf = (float*)w;  w += (size_t)BB * 2 * NC * DINNER * 4;   // 1.23 MB
    __bf16* Qbuf  = (__bf16*)w; w += (size_t)BB * 2 * NC * DSTATE * DINNER * 2;  // 9.83 MB

    // 1) xz = hidden @ W_in^T, fp32 operands cvt'd on the fly, fused silu
    gemm_silu<<<dim3(600), dim3(256), 0, stream>>>(hidden, W_in, xb, zb);
    // 2) x_dbl + dt, fused (225 blocks); also zeros ymean
    gemm2_dt<<<dim3(225), dim3(256), 0, stream>>>(xb, W_xproj, W_dt, b_dt, dtBC, dtb, ymean);
    // 3) chunked scan (4800 waves/pass); pass3 accumulates ymean via atomics
    scan_pass1<<<dim3(NC * 4, 2, BB), dim3(128), 0, stream>>>(
        dtb, xb, dtBC, A_log_f, A_log_b, sdtBuf, Qbuf);
    scan_stitch<<<dim3(256), dim3(256), 0, stream>>>(sdtBuf, A_log_f, A_log_b, Qbuf);
    scan_pass3<<<dim3(NC * 4, 2, BB), dim3(128), 0, stream>>>(
        dtb, xb, dtBC, A_log_f, A_log_b, D_f, D_b, zb, Qbuf, yb, ymean);
    // 4) gating (mean folded in as x(1/LL); fp32 weights)
    gemv1024<0><<<dim3(1024), dim3(256), 0, stream>>>(ymean, W_glob, b_glob, t1, 1.f / (float)LL);
    gemv1024<1><<<dim3(1024), dim3(256), 0, stream>>>(t1, W_gate, b_gate, gbuf, 1.f);
    // 5) out = (y ∘ g) @ W_out^T, KS=4 LDS-combined (600 blocks); g fused in
    gemm8_comb<<<dim3(600), dim3(256), 0, stream>>>(yb, W_out, gbuf, out);
}

// Round 17
// 208.171 us; speedup vs baseline: 1.0736x; 1.0736x over previous
//
#include <hip/hip_runtime.h>
#include <hip/hip_bf16.h>

// Problem constants
#define BB 4
#define LL 900
#define DMODEL 256
#define DSTATE 16
#define DINNER 512
#define DTRANK 16
#define BL (BB*LL)          // 3600
#define NC 75               // scan chunks
#define LC 12               // steps per chunk; NC*LC == LL

typedef __bf16 bf16x8 __attribute__((ext_vector_type(8)));
typedef float f32x4 __attribute__((ext_vector_type(4)));

__device__ __forceinline__ float silu_f(float v) { return v / (1.f + __expf(-v)); }

// ---------------------------------------------------------------------------
// One-time bf16 conversion of GEMM operands (re-read many times -> worth it;
// round 16 proved on-the-fly conversion in the GEMMs costs +15us) + ymean=0.
// ---------------------------------------------------------------------------
#define N_HID  (BL*DMODEL)             // 921600
#define N_WIN  (2*DINNER*DMODEL)       // 262144
#define N_WXP  (48*DINNER)             // 24576
#define N_WOUT (DMODEL*2*DINNER)       // 262144
#define N_TOT  (N_HID+N_WIN+N_WXP+N_WOUT)
__global__ void cvt_inputs(const float* __restrict__ hidden, const float* __restrict__ Win,
                           const float* __restrict__ Wxp, const float* __restrict__ Wout,
                           __bf16* __restrict__ hh, __bf16* __restrict__ wih,
                           __bf16* __restrict__ wxh, __bf16* __restrict__ woh,
                           float* __restrict__ ymean)
{
    int idx = blockIdx.x * 256 + threadIdx.x;
    if (idx < BB * 1024) ymean[idx] = 0.f;     // accumulator for pass3 atomics
    if (idx >= N_TOT) return;
    const float* src; __bf16* dst; int off;
    if (idx < N_HID)                        { src = hidden; dst = hh;  off = idx; }
    else if (idx < N_HID+N_WIN)             { src = Win;    dst = wih; off = idx - N_HID; }
    else if (idx < N_HID+N_WIN+N_WXP)       { src = Wxp;    dst = wxh; off = idx - N_HID - N_WIN; }
    else                                    { src = Wout;   dst = woh; off = idx - N_HID - N_WIN - N_WXP; }
    dst[off] = (__bf16)src[off];
}

// ---------------------------------------------------------------------------
// gemm1: xz = hidden @ W_in^T (M=3600,N=1024,K=256), bf16 MFMA, fused silu.
// Wave tile 48x32 (WM=3,WN=2); 2400 waves.
// ---------------------------------------------------------------------------
__launch_bounds__(256)
__global__ void gemm_silu(const __bf16* __restrict__ A, const __bf16* __restrict__ B,
                          __bf16* __restrict__ xb, __bf16* __restrict__ zb)
{
    constexpr int WM = 3, WN = 2, K = 256, nk = K >> 5;
    constexpr int M = BL, N = 2 * DINNER;
    int wave = (blockIdx.x * 256 + threadIdx.x) >> 6;
    int ntN = N / (16 * WN);
    if (wave >= (M / (16 * WM)) * ntN) return;
    int tm = wave / ntN, tn = wave % ntN;
    int lane = threadIdx.x & 63, q = lane >> 4, r = lane & 15;

    const bf16x8* Ar[WM]; const bf16x8* Br[WN];
    #pragma unroll
    for (int mi = 0; mi < WM; ++mi)
        Ar[mi] = (const bf16x8*)(A + (size_t)(tm * 48 + mi * 16 + r) * K);
    #pragma unroll
    for (int ni = 0; ni < WN; ++ni)
        Br[ni] = (const bf16x8*)(B + (size_t)(tn * 32 + ni * 16 + r) * K);
    f32x4 acc[WM][WN];
    #pragma unroll
    for (int mi = 0; mi < WM; ++mi)
        #pragma unroll
        for (int ni = 0; ni < WN; ++ni) acc[mi][ni] = (f32x4){0.f,0.f,0.f,0.f};

    #pragma unroll
    for (int kk = 0; kk < nk; ++kk) {
        int idx = kk * 4 + q;
        bf16x8 av[WM], bv[WN];
        #pragma unroll
        for (int mi = 0; mi < WM; ++mi) av[mi] = Ar[mi][idx];
        #pragma unroll
        for (int ni = 0; ni < WN; ++ni) bv[ni] = Br[ni][idx];
        #pragma unroll
        for (int mi = 0; mi < WM; ++mi)
            #pragma unroll
            for (int ni = 0; ni < WN; ++ni)
                acc[mi][ni] = __builtin_amdgcn_mfma_f32_16x16x32_bf16(av[mi], bv[ni], acc[mi][ni], 0, 0, 0);
    }
    #pragma unroll
    for (int mi = 0; mi < WM; ++mi)
        #pragma unroll
        for (int ni = 0; ni < WN; ++ni) {
            int col = tn * 32 + ni * 16 + r;
            #pragma unroll
            for (int i = 0; i < 4; ++i) {
                int row = tm * 48 + mi * 16 + q * 4 + i;
                float s = silu_f(acc[mi][ni][i]);
                if (col < DINNER) xb[(size_t)row * DINNER + col] = (__bf16)s;
                else              zb[(size_t)row * DINNER + (col - DINNER)] = (__bf16)s;
            }
        }
}

// ---------------------------------------------------------------------------
// gemm2 + dt fused: x_dbl = x @ W_xproj^T (M=3600,N=48,K=512), KS=4 K-split
// combined in LDS; then dt = softplus(...) packed with x into one uint32
// (hi16 = dt bf16 bits, lo16 = x bf16 bits) -> one 4B load/step in the scan.
// ---------------------------------------------------------------------------
__launch_bounds__(256)
__global__ void gemm2_dt(const __bf16* __restrict__ A, const __bf16* __restrict__ B,
                         const float* __restrict__ Wdt, const float* __restrict__ bdt,
                         float* __restrict__ dtBC, unsigned* __restrict__ pak)
{
    constexpr int WN = 3, K = 512, KSL = 128, nk = KSL >> 5;   // 4 chunks
    __shared__ float lds[4][16 * 48];
    int tm = blockIdx.x;                       // 225 tiles (16 rows each)
    int wv = threadIdx.x >> 6, kOff = wv * KSL;
    int lane = threadIdx.x & 63, q = lane >> 4, r = lane & 15;

    const bf16x8* Ar = (const bf16x8*)(A + (size_t)(tm * 16 + r) * K + kOff);
    const bf16x8* Br[WN];
    #pragma unroll
    for (int ni = 0; ni < WN; ++ni)
        Br[ni] = (const bf16x8*)(B + (size_t)(ni * 16 + r) * K + kOff);
    f32x4 acc[WN];
    #pragma unroll
    for (int ni = 0; ni < WN; ++ni) acc[ni] = (f32x4){0.f,0.f,0.f,0.f};

    #pragma unroll
    for (int kk = 0; kk < nk; ++kk) {
        int idx = kk * 4 + q;
        bf16x8 av = Ar[idx];
        #pragma unroll
        for (int ni = 0; ni < WN; ++ni)
            acc[ni] = __builtin_amdgcn_mfma_f32_16x16x32_bf16(av, Br[ni][idx], acc[ni], 0, 0, 0);
    }
    #pragma unroll
    for (int ni = 0; ni < WN; ++ni) {
        int col = ni * 16 + r;
        #pragma unroll
        for (int i = 0; i < 4; ++i)
            lds[wv][(q * 4 + i) * 48 + col] = acc[ni][i];
    }
    __syncthreads();
    for (int e = threadIdx.x; e < 16 * 48; e += 256) {
        float s = lds[0][e] + lds[1][e] + lds[2][e] + lds[3][e];
        lds[0][e] = s;
        int row = e / 48, col = e % 48;
        dtBC[(size_t)(tm * 16 + row) * 48 + col] = s;
    }
    __syncthreads();
    const unsigned short* xbits = (const unsigned short*)A;
    for (int it = 0; it < 32; ++it) {
        int e = threadIdx.x + it * 256;        // 8192
        int row = e >> 9, d = e & 511;
        const float* wr = Wdt + (size_t)d * DTRANK;
        float s = bdt[d];
        #pragma unroll
        for (int k = 0; k < DTRANK; ++k) s = fmaf(lds[0][row * 48 + k], wr[k], s);
        float dtv = (s > 15.f) ? s : __logf(1.f + __expf(s));
        unsigned short db = __builtin_bit_cast(unsigned short, (__bf16)dtv);
        size_t o = (size_t)(tm * 16 + row) * DINNER + d;
        pak[o] = ((unsigned)db << 16) | (unsigned)xbits[o];
    }
}

// unpack: hi16 -> dt (bf16->f32 is a shift), lo16 -> x
__device__ __forceinline__ void unpack(unsigned v, float& dtv, float& u)
{
    dtv = __uint_as_float(v & 0xffff0000u);
    u   = __uint_as_float(v << 16);
}

// ---------------------------------------------------------------------------
// Scan pass 1: per-chunk zero-init run -> Q (end state, bf16), sdt (scalar).
// Q layout: [bd][c][n][d] (d fastest). sdt: [bd][c][d].
// ---------------------------------------------------------------------------
__global__ void scan_pass1(const unsigned* __restrict__ pak,
                           const float* __restrict__ dtBC,
                           const float* __restrict__ AlogF, const float* __restrict__ AlogB,
                           float* __restrict__ sdtBuf, __bf16* __restrict__ Qbuf)
{
    int b = blockIdx.z, dir = blockIdx.y;
    int c = blockIdx.x >> 2, dgrp = blockIdx.x & 3;
    int d = dgrp * 128 + threadIdx.x;
    const float* Alog = dir ? AlogB : AlogF;
    float a2[DSTATE];
    #pragma unroll
    for (int n = 0; n < DSTATE; ++n) a2[n] = -__expf(Alog[d * DSTATE + n]) * 1.44269504f;
    float h[DSTATE];
    #pragma unroll
    for (int n = 0; n < DSTATE; ++n) h[n] = 0.f;
    float sdt = 0.f;

    #pragma unroll 4
    for (int il = 0; il < LC; ++il) {
        int i = c * LC + il;
        int l = dir ? (LL - 1 - i) : i;
        size_t base = (size_t)b * LL + l;
        float dtv, u;
        unpack(pak[base * DINNER + d], dtv, u);
        float du = dtv * u;
        const f32x4* Bp = (const f32x4*)(dtBC + base * 48 + DTRANK);
        f32x4 Bq[4];
        #pragma unroll
        for (int j = 0; j < 4; ++j) Bq[j] = Bp[j];
        sdt += dtv;
        #pragma unroll
        for (int n = 0; n < DSTATE; ++n)
            h[n] = fmaf(exp2f(dtv * a2[n]), h[n], du * Bq[n >> 2][n & 3]);
    }
    int bd = b * 2 + dir;
    sdtBuf[((size_t)bd * NC + c) * DINNER + d] = sdt;
    size_t o = (((size_t)bd * NC + c) * DSTATE) * DINNER + d;
    #pragma unroll
    for (int n = 0; n < DSTATE; ++n)
        Qbuf[o + (size_t)n * DINNER] = (__bf16)h[n];
}

// Pass 2: stitch in place on Qbuf (H0 overwrites Q); P recomputed from sdt.
__global__ void scan_stitch(const float* __restrict__ sdtBuf,
                            const float* __restrict__ AlogF, const float* __restrict__ AlogB,
                            __bf16* __restrict__ Qbuf)
{
    int idx = blockIdx.x * 256 + threadIdx.x;   // 65536
    int bd = idx >> 13;
    int rem = idx & 8191;           // n*512 + d
    int n = rem >> 9, d = rem & 511;
    const float* Alog = (bd & 1) ? AlogB : AlogF;
    float a2 = -__expf(Alog[d * DSTATE + n]) * 1.44269504f;
    size_t qbase = (size_t)bd * NC * 8192 + rem;
    size_t sbase = (size_t)bd * NC * DINNER + d;
    float H = 0.f;
    for (int cb = 0; cb < NC; cb += 15) {
        float Qv[15], Sv[15];
        #pragma unroll
        for (int j = 0; j < 15; ++j) {
            Qv[j] = (float)Qbuf[qbase + (size_t)(cb + j) * 8192];
            Sv[j] = sdtBuf[sbase + (size_t)(cb + j) * DINNER];
        }
        #pragma unroll
        for (int j = 0; j < 15; ++j) {
            Qbuf[qbase + (size_t)(cb + j) * 8192] = (__bf16)H;   // H0 for chunk
            H = fmaf(exp2f(Sv[j] * a2), H, Qv[j]);
        }
    }
}

// Pass 3: re-run chunk from true initial state (bf16 H0 in Qbuf); emit y;
// accumulate the L-mean numerator straight into ymean via atomics.
__global__ void scan_pass3(const unsigned* __restrict__ pak,
                           const float* __restrict__ dtBC,
                           const float* __restrict__ AlogF, const float* __restrict__ AlogB,
                           const float* __restrict__ Df, const float* __restrict__ Db,
                           const __bf16* __restrict__ zb,
                           const __bf16* __restrict__ H0buf,
                           __bf16* __restrict__ yb,        // [B,L,1024]
                           float* __restrict__ ymean)      // [B,1024] (pre-zeroed)
{
    int b = blockIdx.z, dir = blockIdx.y;
    int c = blockIdx.x >> 2, dgrp = blockIdx.x & 3;
    int d = dgrp * 128 + threadIdx.x;
    const float* Alog = dir ? AlogB : AlogF;
    float a2[DSTATE];
    #pragma unroll
    for (int n = 0; n < DSTATE; ++n) a2[n] = -__expf(Alog[d * DSTATE + n]) * 1.44269504f;
    float Dd = dir ? Db[d] : Df[d];
    size_t o = (((size_t)(b * 2 + dir) * NC + c) * DSTATE) * DINNER + d;
    float h[DSTATE];
    #pragma unroll
    for (int n = 0; n < DSTATE; ++n) h[n] = (float)H0buf[o + (size_t)n * DINNER];
    float ysum = 0.f;

    #pragma unroll 4
    for (int il = 0; il < LC; ++il) {
        int i = c * LC + il;
        int l = dir ? (LL - 1 - i) : i;
        size_t base = (size_t)b * LL + l;
        float dtv, u;
        unpack(pak[base * DINNER + d], dtv, u);
        float du = dtv * u;
        const f32x4* Bp = (const f32x4*)(dtBC + base * 48 + DTRANK);
        f32x4 Bq[4], Cq[4];
        #pragma unroll
        for (int j = 0; j < 4; ++j) Bq[j] = Bp[j];
        #pragma unroll
        for (int j = 0; j < 4; ++j) Cq[j] = Bp[4 + j];
        float p = 0.f;
        #pragma unroll
        for (int n = 0; n < DSTATE; ++n) {
            h[n] = fmaf(exp2f(dtv * a2[n]), h[n], du * Bq[n >> 2][n & 3]);
            p = fmaf(h[n], Cq[n >> 2][n & 3], p);
        }
        float zg = (float)zb[base * DINNER + d];
        float yv = (p + Dd * u) * zg;
        size_t yo = base * (2 * DINNER) + dir * DINNER + d;
        yb[yo] = (__bf16)yv;
        ysum += yv;
    }
    atomicAdd(&ymean[b * 1024 + dir * DINNER + d], ysum);
}

// gemv: one wave per (b,j); 4096 waves; fp32 weights (read once each).
template<int SIG>
__global__ void gemv1024(const float* __restrict__ vin,
                         const float* __restrict__ W,
                         const float* __restrict__ bias,
                         float* __restrict__ vout, float scl)
{
    int wv = (blockIdx.x * blockDim.x + threadIdx.x) >> 6;
    int b = wv >> 10, j = wv & 1023;
    int lane = threadIdx.x & 63;
    const float* wr = W + (size_t)j * 1024;
    const float* vr = vin + (size_t)b * 1024;
    float s = 0.f;
    for (int k = lane; k < 1024; k += 64) s = fmaf(vr[k], wr[k], s);
    #pragma unroll
    for (int o = 32; o; o >>= 1) s += __shfl_xor(s, o);
    if (lane == 0) {
        s = s * scl + bias[j];
        vout[wv] = SIG ? (1.f / (1.f + __expf(-s))) : s;
    }
}

// ---------------------------------------------------------------------------
// gemm8: out = (y ∘ g) @ W_out^T (M=3600,N=256,K=1024), KS=4 LDS-combined.
// One 48x32 tile per block; 4 waves = 4 K-slices of 256; g fused on A.
// ---------------------------------------------------------------------------
__launch_bounds__(256)
__global__ void gemm8_comb(const __bf16* __restrict__ A, const __bf16* __restrict__ B,
                           const float* __restrict__ g,   // [BB,1024]
                           float* __restrict__ out)
{
    constexpr int WM = 3, WN = 2, K = 1024, KSL = 256, nk = KSL >> 5;  // 8 chunks
    constexpr int N = DMODEL, ntN = N / (16 * WN);                      // 8
    __shared__ float lds[4][48 * 32];
    int ks = threadIdx.x >> 6;
    int tIdx = blockIdx.x;                     // 600 tiles
    int tm = tIdx / ntN, tn = tIdx % ntN;
    int kOff = ks * KSL;
    int lane = threadIdx.x & 63, q = lane >> 4, r = lane & 15;

    const bf16x8* Ar[WM]; const bf16x8* Br[WN];
    const float* gp[WM];
    #pragma unroll
    for (int mi = 0; mi < WM; ++mi) {
        int grow = tm * 48 + mi * 16 + r;
        Ar[mi] = (const bf16x8*)(A + (size_t)grow * K + kOff);
        gp[mi] = g + (grow / LL) * 1024 + kOff;
    }
    #pragma unroll
    for (int ni = 0; ni < WN; ++ni)
        Br[ni] = (const bf16x8*)(B + (size_t)(tn * 32 + ni * 16 + r) * K + kOff);
    f32x4 acc[WM][WN];
    #pragma unroll
    for (int mi = 0; mi < WM; ++mi)
        #pragma unroll
        for (int ni = 0; ni < WN; ++ni) acc[mi][ni] = (f32x4){0.f,0.f,0.f,0.f};

    #pragma unroll
    for (int kk = 0; kk < nk; ++kk) {
        int idx = kk * 4 + q;
        bf16x8 av[WM], bv[WN];
        #pragma unroll
        for (int mi = 0; mi < WM; ++mi) {
            bf16x8 a = Ar[mi][idx];
            const f32x4* gv = (const f32x4*)(gp[mi] + idx * 8);
            f32x4 g0 = gv[0], g1 = gv[1];
            #pragma unroll
            for (int j = 0; j < 4; ++j) a[j] = (__bf16)((float)a[j] * g0[j]);
            #pragma unroll
            for (int j = 0; j < 4; ++j) a[4 + j] = (__bf16)((float)a[4 + j] * g1[j]);
            av[mi] = a;
        }
        #pragma unroll
        for (int ni = 0; ni < WN; ++ni) bv[ni] = Br[ni][idx];
        #pragma unroll
        for (int mi = 0; mi < WM; ++mi)
            #pragma unroll
            for (int ni = 0; ni < WN; ++ni)
                acc[mi][ni] = __builtin_amdgcn_mfma_f32_16x16x32_bf16(av[mi], bv[ni], acc[mi][ni], 0, 0, 0);
    }
    #pragma unroll
    for (int mi = 0; mi < WM; ++mi)
        #pragma unroll
        for (int ni = 0; ni < WN; ++ni) {
            int col = ni * 16 + r;
            #pragma unroll
            for (int i = 0; i < 4; ++i)
                lds[ks][(mi * 16 + q * 4 + i) * 32 + col] = acc[mi][ni][i];
        }
    __syncthreads();
    for (int e = threadIdx.x; e < 1536; e += 256) {
        int row = e >> 5, col = e & 31;
        int gm = tm * 48 + row, gn = tn * 32 + col;
        out[(size_t)gm * N + gn] = lds[0][e] + lds[1][e] + lds[2][e] + lds[3][e];
    }
}

// ---------------------------------------------------------------------------
extern "C" void kernel_launch(void* const* d_in, const int* in_sizes, int n_in,
                              void* d_out, int out_size, void* d_ws, size_t ws_size,
                              hipStream_t stream)
{
    const float* hidden  = (const float*)d_in[0];
    const float* W_in    = (const float*)d_in[1];
    const float* W_xproj = (const float*)d_in[2];
    const float* W_dt    = (const float*)d_in[3];
    const float* b_dt    = (const float*)d_in[4];
    const float* A_log_f = (const float*)d_in[5];
    const float* A_log_b = (const float*)d_in[6];
    const float* D_f     = (const float*)d_in[7];
    const float* D_b     = (const float*)d_in[8];
    const float* W_glob  = (const float*)d_in[9];
    const float* b_glob  = (const float*)d_in[10];
    const float* W_gate  = (const float*)d_in[11];
    const float* b_gate  = (const float*)d_in[12];
    const float* W_out   = (const float*)d_in[13];
    float* out = (float*)d_out;

    // workspace (~40 MB)
    char* w = (char*)d_ws;
    __bf16* xb    = (__bf16*)w; w += (size_t)BL * DINNER * 2;            // 3.69 MB
    __bf16* zb    = (__bf16*)w; w += (size_t)BL * DINNER * 2;            // 3.69 MB
    float* dtBC   = (float*)w;  w += (size_t)BL * 48 * 4;                // 0.69 MB
    unsigned* pak = (unsigned*)w; w += (size_t)BL * DINNER * 4;          // 7.37 MB
    __bf16* yb    = (__bf16*)w; w += (size_t)BL * 2 * DINNER * 2;        // 7.37 MB
    float* ymean  = (float*)w;  w += (size_t)BB * 1024 * 4;
    float* t1     = (float*)w;  w += (size_t)BB * 1024 * 4;
    float* gbuf   = (float*)w;  w += (size_t)BB * 1024 * 4;
    __bf16* hh    = (__bf16*)w; w += (size_t)N_HID * 2;                  // 1.84 MB
    __bf16* wih   = (__bf16*)w; w += (size_t)N_WIN * 2;
    __bf16* wxh   = (__bf16*)w; w += (size_t)N_WXP * 2;
    __bf16* woh   = (__bf16*)w; w += (size_t)N_WOUT * 2;
    float* sdtBuf = (float*)w;  w += (size_t)BB * 2 * NC * DINNER * 4;   // 1.23 MB
    __bf16* Qbuf  = (__bf16*)w; w += (size_t)BB * 2 * NC * DSTATE * DINNER * 2;  // 9.83 MB

    // 0) bf16 conversion of hidden + GEMM weights; zero ymean
    cvt_inputs<<<dim3((N_TOT + 255) / 256), dim3(256), 0, stream>>>(
        hidden, W_in, W_xproj, W_out, hh, wih, wxh, woh, ymean);
    // 1) xz = hidden @ W_in^T, fused silu (2400 waves)
    gemm_silu<<<dim3(600), dim3(256), 0, stream>>>(hh, wih, xb, zb);
    // 2) x_dbl + dt(packed with x) fused (225 blocks)
    gemm2_dt<<<dim3(225), dim3(256), 0, stream>>>(xb, wxh, W_dt, b_dt, dtBC, pak);
    // 3) chunked scan (4800 waves/pass); pass3 accumulates ymean via atomics
    scan_pass1<<<dim3(NC * 4, 2, BB), dim3(128), 0, stream>>>(
        pak, dtBC, A_log_f, A_log_b, sdtBuf, Qbuf);
    scan_stitch<<<dim3(256), dim3(256), 0, stream>>>(sdtBuf, A_log_f, A_log_b, Qbuf);
    scan_pass3<<<dim3(NC * 4, 2, BB), dim3(128), 0, stream>>>(
        pak, dtBC, A_log_f, A_log_b, D_f, D_b, zb, Qbuf, yb, ymean);
    // 4) gating (mean folded in as x(1/LL); fp32 weights)
    gemv1024<0><<<dim3(1024), dim3(256), 0, stream>>>(ymean, W_glob, b_glob, t1, 1.f / (float)LL);
    gemv1024<1><<<dim3(1024), dim3(256), 0, stream>>>(t1, W_gate, b_gate, gbuf, 1.f);
    // 5) out = (y ∘ g) @ W_out^T, KS=4 LDS-combined (600 blocks); g fused in
    gemm8_comb<<<dim3(600), dim3(256), 0, stream>>>(yb, woh, gbuf, out);
}